// Round 5
// baseline (448.176 us; speedup 1.0000x reference)
//
#include <hip/hip_runtime.h>
#include <hip/hip_fp16.h>

// GCN 3-layer encoder for MI355X.
// dinv folded into H (Hs = dinv*h, fp16); EW packs (src<<15 | w_q15) in 4 B.
// Build: two-phase, 64-node partitions (p=dst>>6) so slot counters live in
// LDS (R4: killed the 1.6M global-RMW bottleneck; 450->436 us).
// R5: occupancy round.
//  - k_bin 512x1024 (was 256x256): build was 12.5% occupancy, latency-bound
//    double-scan. Tail atomics grow to ~635K but spread over 1563 lines.
//  - k_agg 1024-thr blocks (16 nodes): 6250 blocks instead of 25000; fewer
//    block-scheduling events, occupancy 72->~95%. k_agg traffic is within 9%
//    of the 8xL2-duplication lower bound (192 vs 176 MB) -- bytes are
//    optimal, only rate/occupancy left.
//  - k_pre: W reads coalesced (source-major), scattered 2B writes absorbed
//    by L2 (wt buffers are 32KB, resident).
// k_pre(init+wprep) -> k_bin -> k_fill -> [gemm_mfma -> aggregate] x3

typedef __attribute__((ext_vector_type(8))) _Float16 f16x8;
typedef __attribute__((ext_vector_type(4))) float f32x4;
typedef unsigned long long u64;

#define WQ_BITS 15
#define WQ_SCALE 32768.0f
#define WQ_MASK 32767u
#define MAXNP 2048

#define RL(v, k) __builtin_amdgcn_readlane((v), (k))

// Fused: zero tails + transpose W0/W1/W2 (fp32 [k][n]) into f16 Wt [n][k].
// Reads coalesced (id = k-major source order); scattered 2B writes land in
// the L2-resident 32KB wt buffers.
__global__ __launch_bounds__(256) void k_pre(int* tail, int NP,
                                             const float* __restrict__ W0,
                                             const float* __restrict__ W1,
                                             const float* __restrict__ W2,
                                             __half* __restrict__ wt0,
                                             __half* __restrict__ wt1,
                                             __half* __restrict__ wt2) {
    int id = blockIdx.x * 256 + threadIdx.x;
    if (id < NP) tail[id] = 0;
    if (id < 16384) {
        int k = id >> 7, n = id & 127;           // read W0 row-major (coalesced)
        wt0[n * 128 + k] = __float2half(W0[id]); // write wt[n][k] scattered
    } else if (id < 32768) {
        int j = id - 16384, k = j >> 7, n = j & 127;
        wt1[n * 128 + k] = __float2half(W1[j]);
    } else if (id < 40960) {
        int j = id - 32768, k = j >> 6, n = j & 63;  // W2 is [128][64]
        wt2[n * 128 + k] = __float2half(W2[j]);
    }
}

// Phase 1: bin edges into NP per-node-range lists. Two passes over a
// contiguous per-block chunk (2nd pass mostly L2/LLC-hot). Global atomics:
// one per (block, nonzero partition) -- ~635K over 1563 spread words.
__global__ __launch_bounds__(1024) void k_bin(const int* __restrict__ src,
                                              const int* __restrict__ dst,
                                              const float* __restrict__ w,
                                              int* tail, u64* __restrict__ glist,
                                              int E, int ecap, int NP, int shift) {
    __shared__ unsigned int h[MAXNP];
    __shared__ int base[MAXNP];
    const int tid = threadIdx.x;
    const int nb = gridDim.x;
    const int per = (E + nb - 1) / nb;
    const int e0 = blockIdx.x * per;
    const int e1 = (e0 + per < E) ? e0 + per : E;

    for (int i = tid; i < NP; i += 1024) h[i] = 0;
    __syncthreads();
    for (int e = e0 + tid; e < e1; e += 1024) {
        int p = dst[e] >> shift;
        atomicAdd(&h[p], 1u);
    }
    __syncthreads();
    for (int i = tid; i < NP; i += 1024) {
        unsigned int c = h[i];
        base[i] = c ? atomicAdd(&tail[i], (int)c) : 0;
    }
    __syncthreads();
    for (int e = e0 + tid; e < e1; e += 1024) {
        int t = dst[e];  // L2-hot (pass 1 cached it)
        int p = t >> shift;
        int s = __builtin_nontemporal_load(src + e);
        float we = __builtin_nontemporal_load(w + e);
        int wq = (int)(we * WQ_SCALE + 0.5f);
        wq = (wq < (int)WQ_MASK) ? wq : (int)WQ_MASK;
        u64 v = ((u64)(unsigned)t << 32) |
                ((unsigned)s << WQ_BITS) | (unsigned)wq;
        unsigned int idx = atomicSub(&h[p], 1u) - 1u;  // LDS, order-free
        int pos = base[p] + (int)idx;
        if (pos < ecap) glist[(size_t)p * ecap + pos] = v;
    }
}

// Phase 2: one block per partition (64-node range). Slot assignment via LDS
// atomics; EW plain stores into the partition's own L2-resident region.
// Also emits cnt (plain store) and dinv (LDS float accumulation of wq).
__global__ __launch_bounds__(256) void k_fill(const int* __restrict__ tail,
                                              const u64* __restrict__ glist,
                                              int ecap, int* __restrict__ cnt,
                                              float* __restrict__ dinv,
                                              unsigned int* __restrict__ EW,
                                              int cap, int N, int shift) {
    __shared__ unsigned int lcnt[MAXNP];
    __shared__ float lws[MAXNP];
    const int p = blockIdx.x;
    const int np = 1 << shift;
    const int t0 = p << shift;
    for (int i = threadIdx.x; i < np; i += 256) { lcnt[i] = 0; lws[i] = 0.f; }
    __syncthreads();
    int n = tail[p];
    if (n > ecap) n = ecap;
    const u64* L = glist + (size_t)p * ecap;
    for (int j = threadIdx.x; j < n; j += 256) {
        u64 v = L[j];
        int t = (int)(v >> 32);
        int loc = t - t0;
        unsigned int k = atomicAdd(&lcnt[loc], 1u);  // LDS
        if ((int)k < cap) {
            EW[(size_t)t * cap + k] = (unsigned int)v;
            atomicAdd(&lws[loc], (float)((unsigned int)v & WQ_MASK));  // LDS f32
        }
    }
    __syncthreads();
    for (int i = threadIdx.x; i < np; i += 256) {
        int t = t0 + i;
        if (t < N) {
            int c = (int)lcnt[i];
            c = (c < cap) ? c : cap;
            cnt[t] = c;
            dinv[t] = 1.0f / sqrtf(1.0f + lws[i] * (1.0f / WQ_SCALE));
        }
    }
}

// MFMA GEMM: H[N x BN] = dinv[r]*(X[N x 128] @ W[128 x BN]) as fp16.
// Per wave: 16 rows x BN cols. Operand swap: A:=W^T-frag (from Wt[n][k]),
// B:=X^T-frag -> each lane holds 4 consecutive H-cols -> 8 B stores. No LDS.
// dinv read from global (computed by k_fill).
template <int BN, bool XFP32>
__global__ __launch_bounds__(256, 4) void k_gemm(const void* __restrict__ Xv,
                                                 const __half* __restrict__ Wt,
                                                 const float* __restrict__ dinv,
                                                 __half* __restrict__ H, int N) {
    const int tid = threadIdx.x;
    const int lane = tid & 63;
    const int wv = tid >> 6;
    const int m = lane & 15;
    const int quad = lane >> 4;
    const int rb = blockIdx.x * 64;
    const int row = rb + wv * 16 + m;
    const int rowc = (row < N) ? row : (N - 1);

    // Prefetch X-frags for all 4 k-steps (k = s*32 + quad*8 + j).
    f16x8 xf[4];
    if constexpr (XFP32) {
        const float* X = (const float*)Xv;
#pragma unroll
        for (int s = 0; s < 4; s++) {
            const float4* p = (const float4*)(X + (size_t)rowc * 128 + s * 32 + quad * 8);
            float4 u0 = p[0], u1 = p[1];
            f16x8 f;
            f[0] = (_Float16)u0.x; f[1] = (_Float16)u0.y;
            f[2] = (_Float16)u0.z; f[3] = (_Float16)u0.w;
            f[4] = (_Float16)u1.x; f[5] = (_Float16)u1.y;
            f[6] = (_Float16)u1.z; f[7] = (_Float16)u1.w;
            xf[s] = f;
        }
    } else {
        const __half* X = (const __half*)Xv;
#pragma unroll
        for (int s = 0; s < 4; s++)
            xf[s] = *(const f16x8*)(X + (size_t)rowc * 128 + s * 32 + quad * 8);
    }

    constexpr int NT = BN / 16;
    f32x4 acc[NT];
#pragma unroll
    for (int t = 0; t < NT; t++) acc[t] = (f32x4){0.f, 0.f, 0.f, 0.f};

#pragma unroll
    for (int s = 0; s < 4; s++) {
#pragma unroll
        for (int t = 0; t < NT; t++) {
            f16x8 wf = *(const f16x8*)(Wt + (size_t)(t * 16 + m) * 128 + s * 32 + quad * 8);
            acc[t] = __builtin_amdgcn_mfma_f32_16x16x32_f16(wf, xf[s], acc[t], 0, 0, 0);
        }
    }

    if (row < N) {
        float sc = dinv[row];
#pragma unroll
        for (int t = 0; t < NT; t++) {
            __half2 h0 = __floats2half2_rn(sc * acc[t][0], sc * acc[t][1]);
            __half2 h1 = __floats2half2_rn(sc * acc[t][2], sc * acc[t][3]);
            __half2* dstp = (__half2*)(H + (size_t)row * BN + t * 16 + quad * 4);
            dstp[0] = h0;
            dstp[1] = h1;
        }
    }
}

// Aggregate: out[t] = dinv[t] * (sum_e w_e * Hs[src_e] + Hs[t]) + b
// 16 nodes per 1024-thr block (wave per node); Hs fp16 (dinv-prescaled),
// fp32 accum; packed meta, one readlane/edge. DOUT=128 -> fp16 bufA;
// DOUT=64 -> fp32 d_out.
template <int DOUT, bool RELU>
__global__ __launch_bounds__(1024) void k_agg(const __half* __restrict__ H,
                                              const unsigned int* __restrict__ EW,
                                              const int* __restrict__ cnt,
                                              const float* __restrict__ dinv,
                                              const float* __restrict__ bias,
                                              void* __restrict__ Outv,
                                              int N, int cap) {
    int node = blockIdx.x * 16 + (threadIdx.x >> 6);
    if (node >= N) return;
    const int lane = threadIdx.x & 63;

    int c = cnt[node];  // wave-uniform
    c = (c < cap) ? c : cap;

    unsigned int meta = 0;
    if (lane < c) meta = EW[(size_t)node * cap + lane];

    float dt = dinv[node];

    if constexpr (DOUT == 128) {
        const __half2* H2 = reinterpret_cast<const __half2*>(H);
        float2 hs = __half22float2(H2[(size_t)node * 64 + lane]);
        float a0 = hs.x, a1 = hs.y;  // self term, weight 1.0
        int k = 0;
        for (; k + 8 <= c; k += 8) {
            __half2 hr[8]; float w[8];
#pragma unroll
            for (int u = 0; u < 8; u++) {
                unsigned int mm = RL(meta, k + u);
                w[u] = (float)(mm & WQ_MASK) * (1.0f / WQ_SCALE);
                hr[u] = H2[(size_t)(mm >> WQ_BITS) * 64 + lane];
            }
#pragma unroll
            for (int u = 0; u < 8; u++) {
                float2 hv = __half22float2(hr[u]);
                a0 = fmaf(w[u], hv.x, a0);
                a1 = fmaf(w[u], hv.y, a1);
            }
        }
        for (; k + 4 <= c; k += 4) {
            __half2 hr[4]; float w[4];
#pragma unroll
            for (int u = 0; u < 4; u++) {
                unsigned int mm = RL(meta, k + u);
                w[u] = (float)(mm & WQ_MASK) * (1.0f / WQ_SCALE);
                hr[u] = H2[(size_t)(mm >> WQ_BITS) * 64 + lane];
            }
#pragma unroll
            for (int u = 0; u < 4; u++) {
                float2 hv = __half22float2(hr[u]);
                a0 = fmaf(w[u], hv.x, a0);
                a1 = fmaf(w[u], hv.y, a1);
            }
        }
        for (; k < c; k++) {
            unsigned int mm = RL(meta, k);
            float w = (float)(mm & WQ_MASK) * (1.0f / WQ_SCALE);
            float2 hv = __half22float2(H2[(size_t)(mm >> WQ_BITS) * 64 + lane]);
            a0 = fmaf(w, hv.x, a0);
            a1 = fmaf(w, hv.y, a1);
        }
        float2 b = reinterpret_cast<const float2*>(bias)[lane];
        a0 = fmaf(dt, a0, b.x);
        a1 = fmaf(dt, a1, b.y);
        if (RELU) { a0 = fmaxf(a0, 0.f); a1 = fmaxf(a1, 0.f); }
        reinterpret_cast<__half2*>(Outv)[(size_t)node * 64 + lane] = __floats2half2_rn(a0, a1);
    } else {  // DOUT == 64, fp32 out
        float a = __half2float(H[(size_t)node * 64 + lane]);  // self term
        int k = 0;
        for (; k + 8 <= c; k += 8) {
            __half hr[8]; float w[8];
#pragma unroll
            for (int u = 0; u < 8; u++) {
                unsigned int mm = RL(meta, k + u);
                w[u] = (float)(mm & WQ_MASK) * (1.0f / WQ_SCALE);
                hr[u] = H[(size_t)(mm >> WQ_BITS) * 64 + lane];
            }
#pragma unroll
            for (int u = 0; u < 8; u++) a = fmaf(w[u], __half2float(hr[u]), a);
        }
        for (; k < c; k++) {
            unsigned int mm = RL(meta, k);
            float w = (float)(mm & WQ_MASK) * (1.0f / WQ_SCALE);
            a = fmaf(w, __half2float(H[(size_t)(mm >> WQ_BITS) * 64 + lane]), a);
        }
        a = fmaf(dt, a, bias[lane]);
        if (RELU) a = fmaxf(a, 0.f);
        ((float*)Outv)[(size_t)node * 64 + lane] = a;
    }
}

extern "C" void kernel_launch(void* const* d_in, const int* in_sizes, int n_in,
                              void* d_out, int out_size, void* d_ws, size_t ws_size,
                              hipStream_t stream) {
    const int N = in_sizes[0] / 128;   // x is [N,128]
    const int E = in_sizes[2];         // edge_weight is [E]

    const float* x  = (const float*)d_in[0];
    const int*   ei = (const int*)d_in[1];   // [2,E]: row0=src, row1=dst
    const int*   src = ei;
    const int*   dst = ei + E;
    const float* ew  = (const float*)d_in[2];
    const float* W0 = (const float*)d_in[3];
    const float* b0 = (const float*)d_in[4];
    const float* W1 = (const float*)d_in[5];
    const float* b1 = (const float*)d_in[6];
    const float* W2 = (const float*)d_in[7];
    const float* b2 = (const float*)d_in[8];

    // Partitioning: 64-node ranges; widen shift if N is huge so NP<=MAXNP.
    int shift = 6;
    while ((((N - 1) >> shift) + 1) > MAXNP) shift++;
    const int NP = ((N - 1) >> shift) + 1;

    // Workspace carve; bucket capacity adapts so we never write past d_ws.
    size_t fixed = (((size_t)N * 4 + 255) & ~(size_t)255)            // cnt
                 + (((size_t)N * 4 + 255) & ~(size_t)255)            // dinv
                 + 2 * (((size_t)N * 128 * 2 + 255) & ~(size_t)255)  // bufH, bufA fp16
                 + 3 * 33024                                         // wt0,wt1,wt2
                 + (((size_t)NP * 4 + 255) & ~(size_t)255)           // tail
                 + 2048;
    int cap = 64;
    if (ws_size > fixed) {
        size_t avail = (ws_size - fixed) / ((size_t)N * 4);
        if (avail < (size_t)cap) cap = (int)avail;
    } else {
        cap = 0;
    }

    char* p = (char*)d_ws;
    auto alloc = [&](size_t bytes) -> void* {
        void* r = (void*)p;
        p += (bytes + 255) & ~(size_t)255;
        return r;
    };
    int*          cnt  = (int*)alloc((size_t)N * 4);
    float*        dinv = (float*)alloc((size_t)N * 4);
    unsigned int* EW   = (unsigned int*)alloc((size_t)N * cap * 4);
    __half*       bufH = (__half*)alloc((size_t)N * 128 * 2);
    __half*       bufA = (__half*)alloc((size_t)N * 128 * 2);
    __half*       wt0  = (__half*)alloc(16384 * 2);
    __half*       wt1  = (__half*)alloc(16384 * 2);
    __half*       wt2  = (__half*)alloc(8192 * 2);
    int*          tail = (int*)alloc((size_t)NP * 4);

    // Phase-1 bin lists alias bufH (dead until gemm0): NP lists of ecap u64.
    u64* glist = (u64*)bufH;
    int  ecap  = (int)(((size_t)N * 128 * 2) / ((size_t)NP * 8));  // ~2047 here

    dim3 blk(256);
    dim3 blkK(1024);
    int preN = (NP > 40960) ? NP : 40960;
    dim3 gPre((preN + 255) / 256);
    dim3 gBin(512);    // 2 blocks/CU x 16 waves = full occupancy
    dim3 gFill(NP);    // 1 block per 64-node partition
    dim3 gGemm((N + 63) / 64);
    dim3 gWave((N + 15) / 16);

    k_pre<<<gPre, blk, 0, stream>>>(tail, NP, W0, W1, W2, wt0, wt1, wt2);
    k_bin<<<gBin, blkK, 0, stream>>>(src, dst, ew, tail, glist, E, ecap, NP, shift);
    k_fill<<<gFill, blk, 0, stream>>>(tail, glist, ecap, cnt, dinv, EW, cap, N, shift);

    // layer 0 (x fp32 -> cvt in-kernel)
    k_gemm<128, true><<<gGemm, blk, 0, stream>>>(x, wt0, dinv, bufH, N);
    k_agg<128, true><<<gWave, blkK, 0, stream>>>(bufH, EW, cnt, dinv, b0, bufA, N, cap);

    // layer 1
    k_gemm<128, false><<<gGemm, blk, 0, stream>>>(bufA, wt1, dinv, bufH, N);
    k_agg<128, true><<<gWave, blkK, 0, stream>>>(bufH, EW, cnt, dinv, b1, bufA, N, cap);

    // layer 2 (no relu, fp32 out)
    k_gemm<64, false><<<gGemm, blk, 0, stream>>>(bufA, wt2, dinv, bufH, N);
    k_agg<64, false><<<gWave, blkK, 0, stream>>>(bufH, EW, cnt, dinv, b2,
                                                 d_out, N, cap);
}